// Round 8
// baseline (148.510 us; speedup 1.0000x reference)
//
#include <hip/hip_runtime.h>
#include <math.h>
#include <float.h>

// Problem constants (fixed by the reference)
#define Bn   64
#define Sn   512
#define FWn  6
#define Wn   507     // S - FW + 1
#define WT   16      // windows per block
#define NTILE 32     // 507 windows -> 32 tiles of 16

#define PROWS   21    // projection rows per block (16 windows + FW-1)
#define PSTRIDE 516   // fp16 elems per Pt row: 4*516 halves = 1032 dw row offset
                      // -> q-groups (rows +4) land 8 banks apart: conflict-free

typedef __attribute__((ext_vector_type(8))) _Float16 half8;
typedef __attribute__((ext_vector_type(4))) _Float16 half4;
typedef __attribute__((ext_vector_type(4))) float f32x4;

// Fast activations: v_exp_f32 + v_rcp_f32 (1 ulp), NaN-free at extremes.
__device__ __forceinline__ float sigf(float x)  {
    return __builtin_amdgcn_rcpf(1.0f + __expf(-x));
}
__device__ __forceinline__ float tanh_(float x) {
    return 1.0f - 2.0f * __builtin_amdgcn_rcpf(__expf(2.0f * x) + 1.0f);
}

// ---------------------------------------------------------------------------
// Kernel 0: pack w_ih and w_hh (both [512][128] f32) into fp16 B-fragment
// order for mfma_f32_16x16x32_f16:
//   pack[((nt*4 + ks)*64 + lane)*8 + j] = w[nt*16 + (lane&15)][ks*32 + (lane>>4)*8 + j]
// Row-tile nt = g*8 + ut (gate g, unit-tile ut). 65536 elements each.
// ---------------------------------------------------------------------------
__global__ void __launch_bounds__(256)
pack_w_kernel(const float* __restrict__ w_ih, const float* __restrict__ w_hh,
              _Float16* __restrict__ wih_p, _Float16* __restrict__ whh_p)
{
    const int idx = blockIdx.x * 256 + threadIdx.x;      // 0..65535
    const int j  = idx & 7;
    const int L  = (idx >> 3) & 63;
    const int ks = (idx >> 9) & 3;
    const int nt = idx >> 11;
    const int row = nt * 16 + (L & 15);
    const int col = ks * 32 + (L >> 4) * 8 + j;
    wih_p[idx] = (_Float16)w_ih[row * 128 + col];
    whh_p[idx] = (_Float16)w_hh[row * 128 + col];
}

// ---------------------------------------------------------------------------
// Kernel 1 (fused MFMA LSTM), 16 windows/block, 512 threads (8 waves).
//   Wave wv owns unit-tile ut = wv (16 hidden units).
//   Phase 1: x-projection for rows [w0, w0+20] computed ONCE via MFMA, stored
//     to LDS Pt as PACKED FP16 half4 {i,f,g,o} per (row,unit)  (21.7 KB vs
//     43.3 KB fp32 in R7 -> 4 blocks/CU instead of 2-3: the R7 limiter was
//     occupancy 39% with a 51.7 KB LDS footprint).
//   Phase 2: 6 steps; acc init = half4 Pt read + cvt; h-proj = 16 MFMA from
//     register-resident whh B-frags; h exchanged via 8 KB double-buffered
//     A-fragment LDS, 1 barrier/step.
//   NOTE: no min-waves launch bound — R3 showed a forced VGPR cap causes
//   catastrophic scratch spill. (R7 measured VGPR=56; huge headroom.)
// grid 64*32, block 512.
// ---------------------------------------------------------------------------
__global__ void __launch_bounds__(512)
lstm_kernel(const int* __restrict__ inputs, const float* __restrict__ embed,
            const _Float16* __restrict__ wih_p, const _Float16* __restrict__ whh_p,
            const float* __restrict__ b_ih, const float* __restrict__ b_hh,
            float* __restrict__ partial)
{
    __shared__ __align__(16) _Float16 Pt[PROWS * PSTRIDE];  // 21.7 KB
    __shared__ __align__(16) _Float16 hsA[2][2048];         // 2 x 4 KB
    const int t    = threadIdx.x;
    const int L    = t & 63;
    const int ut   = t >> 6;          // wave index = unit-tile 0..7
    const int b    = blockIdx.x >> 5;
    const int tile = blockIdx.x & 31;
    const int w0   = tile * WT;
    const int q  = L >> 4;
    const int ln = L & 15;
    const int j8 = L & 7;
    const int u  = ut * 16 + ln;      // this lane's hidden unit (B n-index)

    // ---- phase 1: x-proj (2 m-tiles = rows 0..31, stores clamped to 21) ----
    {
        f32x4 accx[2][4];   // [mt][gate], init with bias
#pragma unroll
        for (int g = 0; g < 4; ++g) {
            const float bg = b_ih[g * 128 + u] + b_hh[g * 128 + u];
            accx[0][g] = (f32x4){bg, bg, bg, bg};
            accx[1][g] = accx[0][g];
        }
        int tok[2];
#pragma unroll
        for (int mt = 0; mt < 2; ++mt) {
            int s = w0 + mt * 16 + ln; s = s < 511 ? s : 511;  // clamp (masked at max)
            tok[mt] = inputs[b * Sn + s];
        }
#pragma unroll
        for (int ks = 0; ks < 4; ++ks) {
            half8 ax[2];
#pragma unroll
            for (int mt = 0; mt < 2; ++mt) {
                const float* er = embed + (size_t)tok[mt] * 128 + ks * 32 + q * 8;
                float4 e0 = *(const float4*)er;
                float4 e1 = *(const float4*)(er + 4);
                half8 a;
                a[0] = (_Float16)e0.x; a[1] = (_Float16)e0.y;
                a[2] = (_Float16)e0.z; a[3] = (_Float16)e0.w;
                a[4] = (_Float16)e1.x; a[5] = (_Float16)e1.y;
                a[6] = (_Float16)e1.z; a[7] = (_Float16)e1.w;
                ax[mt] = a;
            }
#pragma unroll
            for (int g = 0; g < 4; ++g) {
                half8 bw = *(const half8*)(wih_p + ((size_t)((g * 8 + ut) * 4 + ks) * 64 + L) * 8);
                accx[0][g] = __builtin_amdgcn_mfma_f32_16x16x32_f16(ax[0], bw, accx[0][g], 0, 0, 0);
                accx[1][g] = __builtin_amdgcn_mfma_f32_16x16x32_f16(ax[1], bw, accx[1][g], 0, 0, 0);
            }
        }
        // store gate-interleaved fp16 Pt rows (predicated to 21 rows)
#pragma unroll
        for (int mt = 0; mt < 2; ++mt)
#pragma unroll
            for (int r = 0; r < 4; ++r) {
                const int sl = mt * 16 + q * 4 + r;
                if (sl < PROWS) {
                    half4 o;
                    o[0] = (_Float16)accx[mt][0][r];
                    o[1] = (_Float16)accx[mt][1][r];
                    o[2] = (_Float16)accx[mt][2][r];
                    o[3] = (_Float16)accx[mt][3][r];
                    *(half4*)&Pt[sl * PSTRIDE + u * 4] = o;
                }
            }
    }

    // register-resident w_hh B-fragments for this wave's unit-tile
    half8 whf[4][4];    // [gate][ks]
#pragma unroll
    for (int g = 0; g < 4; ++g)
#pragma unroll
        for (int ks = 0; ks < 4; ++ks)
            whf[g][ks] = *(const half8*)(whh_p + ((size_t)((g * 8 + ut) * 4 + ks) * 64 + L) * 8);

    __syncthreads();    // Pt visible to all waves

    // h scatter address components (A-fragment layout for unit u, window m)
    const int ks_h = ut >> 1;
    const int qp   = (ut & 1) * 2 + (ln >> 3);

    float cst[4] = {0.f, 0.f, 0.f, 0.f};
    float hh[4];

    // ---- steps 0..5 ----
    for (int st = 0; st < FWn; ++st) {
        if (st > 0) __syncthreads();        // prev step's h scatter visible
        f32x4 acc[4];                       // [gate] over r
#pragma unroll
        for (int r = 0; r < 4; ++r) {
            half4 pv = *(const half4*)&Pt[(q * 4 + r + st) * PSTRIDE + u * 4];
            acc[0][r] = (float)pv[0]; acc[1][r] = (float)pv[1];
            acc[2][r] = (float)pv[2]; acc[3][r] = (float)pv[3];
        }
        if (st > 0) {
            const _Float16* hb = hsA[(st + 1) & 1];   // h(st-1)
#pragma unroll
            for (int ks = 0; ks < 4; ++ks) {
                half8 ah = *(const half8*)(hb + (ks * 64 + L) * 8);
#pragma unroll
                for (int g = 0; g < 4; ++g)
                    acc[g] = __builtin_amdgcn_mfma_f32_16x16x32_f16(ah, whf[g][ks], acc[g], 0, 0, 0);
            }
        }
        _Float16* buf = hsA[st & 1];
#pragma unroll
        for (int r = 0; r < 4; ++r) {
            float ii = sigf(acc[0][r]);
            float ff = sigf(acc[1][r]);
            float gg = tanh_(acc[2][r]);
            float oo = sigf(acc[3][r]);
            float cc = ff * cst[r] + ii * gg;
            cst[r] = cc;
            hh[r] = oo * tanh_(cc);
            if (st < FWn - 1)
                buf[ks_h * 512 + (qp * 16 + q * 4 + r) * 8 + j8] = (_Float16)hh[r];
        }
    }

    // ---- max over this block's 16 windows (mask invalid), reduce across q ----
    float mv = -FLT_MAX;
#pragma unroll
    for (int r = 0; r < 4; ++r) {
        const int w = w0 + q * 4 + r;
        if (w < Wn) mv = fmaxf(mv, hh[r]);
    }
    mv = fmaxf(mv, __shfl_xor(mv, 16));
    mv = fmaxf(mv, __shfl_xor(mv, 32));
    if (q == 0)
        partial[(size_t)(b * NTILE + tile) * 128 + u] = mv;
}

// ---------------------------------------------------------------------------
// Kernel 2: feat[b][u] = max over tiles; out[b][c] = feat . fc_w[c] + fc_b[c]
// grid 64, block 128
// ---------------------------------------------------------------------------
__global__ void __launch_bounds__(128)
final_kernel(const float* __restrict__ partial, const float* __restrict__ fc_w,
             const float* __restrict__ fc_b, float* __restrict__ out)
{
    const int b = blockIdx.x;
    const int u = threadIdx.x;
    float m = -FLT_MAX;
#pragma unroll
    for (int tl = 0; tl < NTILE; ++tl)
        m = fmaxf(m, partial[(size_t)(b * NTILE + tl) * 128 + u]);
    float v0 = m * fc_w[u];
    float v1 = m * fc_w[128 + u];
#pragma unroll
    for (int off = 1; off < 64; off <<= 1) {
        v0 += __shfl_xor(v0, off);
        v1 += __shfl_xor(v1, off);
    }
    __shared__ float red[2][2];
    if ((u & 63) == 0) { red[u >> 6][0] = v0; red[u >> 6][1] = v1; }
    __syncthreads();
    if (u == 0) {
        out[b * 2 + 0] = red[0][0] + red[1][0] + fc_b[0];
        out[b * 2 + 1] = red[0][1] + red[1][1] + fc_b[1];
    }
}

// ---------------------------------------------------------------------------
extern "C" void kernel_launch(void* const* d_in, const int* in_sizes, int n_in,
                              void* d_out, int out_size, void* d_ws, size_t ws_size,
                              hipStream_t stream)
{
    const int*   inputs = (const int*)d_in[0];
    // d_in[1] = lengths : unused by the reference
    const float* embed  = (const float*)d_in[2];
    const float* w_ih   = (const float*)d_in[3];
    const float* w_hh   = (const float*)d_in[4];
    const float* b_ih   = (const float*)d_in[5];
    const float* b_hh   = (const float*)d_in[6];
    const float* fc_w   = (const float*)d_in[7];
    const float* fc_b   = (const float*)d_in[8];
    float* out = (float*)d_out;

    // workspace: partial (1 MiB) | wih_p, whh_p (128 KiB each)
    float*    partial = (float*)d_ws;
    _Float16* wih_p   = (_Float16*)(partial + Bn * NTILE * 128);
    _Float16* whh_p   = wih_p + 65536;

    pack_w_kernel<<<dim3(256), 256, 0, stream>>>(w_ih, w_hh, wih_p, whh_p);
    lstm_kernel<<<dim3(Bn * NTILE), 512, 0, stream>>>(inputs, embed, wih_p, whh_p,
                                                      b_ih, b_hh, partial);
    final_kernel<<<dim3(Bn), 128, 0, stream>>>(partial, fc_w, fc_b, out);
}

// Round 9
// 139.677 us; speedup vs baseline: 1.0632x; 1.0632x over previous
//
#include <hip/hip_runtime.h>
#include <math.h>
#include <float.h>

// Problem constants (fixed by the reference)
#define Bn   64
#define Sn   512
#define FWn  6
#define Wn   507     // S - FW + 1
#define WT   32      // windows per block (2 sub-tiles of 16)
#define NTILE 16     // 507 windows -> 16 tiles of 32

#define PROWS   37    // projection rows per block (32 windows + FW-1)
#define PSTRIDE 516   // fp16 elems per Pt row (1032 B): q-groups land 8 banks
                      // apart per 16-lane phase -> conflict-free b64 access

typedef __attribute__((ext_vector_type(8))) _Float16 half8;
typedef __attribute__((ext_vector_type(4))) _Float16 half4;
typedef __attribute__((ext_vector_type(4))) float f32x4;

// Fast activations: v_exp_f32 + v_rcp_f32 (1 ulp), NaN-free at extremes.
__device__ __forceinline__ float sigf(float x)  {
    return __builtin_amdgcn_rcpf(1.0f + __expf(-x));
}
__device__ __forceinline__ float tanh_(float x) {
    return 1.0f - 2.0f * __builtin_amdgcn_rcpf(__expf(2.0f * x) + 1.0f);
}

// ---------------------------------------------------------------------------
// Kernel 0: pack w_ih and w_hh (both [512][128] f32) into fp16 B-fragment
// order for mfma_f32_16x16x32_f16:
//   pack[((nt*4 + ks)*64 + lane)*8 + j] = w[nt*16 + (lane&15)][ks*32 + (lane>>4)*8 + j]
// Row-tile nt = g*8 + ut (gate g, unit-tile ut). 65536 elements each.
// ---------------------------------------------------------------------------
__global__ void __launch_bounds__(256)
pack_w_kernel(const float* __restrict__ w_ih, const float* __restrict__ w_hh,
              _Float16* __restrict__ wih_p, _Float16* __restrict__ whh_p)
{
    const int idx = blockIdx.x * 256 + threadIdx.x;      // 0..65535
    const int j  = idx & 7;
    const int L  = (idx >> 3) & 63;
    const int ks = (idx >> 9) & 3;
    const int nt = idx >> 11;
    const int row = nt * 16 + (L & 15);
    const int col = ks * 32 + (L >> 4) * 8 + j;
    wih_p[idx] = (_Float16)w_ih[row * 128 + col];
    whh_p[idx] = (_Float16)w_hh[row * 128 + col];
}

// ---------------------------------------------------------------------------
// Kernel 1 (fused MFMA LSTM), 32 windows (2 sub-tiles) per 512-thread block.
//   Wave wv owns unit-tile ut = wv for BOTH sub-tiles: two register-
//   independent streams per barrier interval (2x work per barrier, ILP
//   between A/B hides MFMA + transcendental latency — R8 showed the
//   single-tile step body, ~350 issue-cyc, can't hide the barrier drain).
//   Phase 1: x-proj rows [w0, w0+36] once via MFMA (3 m-tiles) -> fp16 Pt.
//   Phase 2: 6 steps x {2 sub-tiles}; whh register-resident; h via 4 KB/sub
//   double-buffered A-frag LDS; 1 barrier/step.
//   NOTE: no min-waves launch bound — R3 showed a forced VGPR cap causes
//   catastrophic scratch spill. (R8 measured VGPR=56.)
// grid 64*16, block 512.
// ---------------------------------------------------------------------------
__global__ void __launch_bounds__(512)
lstm_kernel(const int* __restrict__ inputs, const float* __restrict__ embed,
            const _Float16* __restrict__ wih_p, const _Float16* __restrict__ whh_p,
            const float* __restrict__ b_ih, const float* __restrict__ b_hh,
            float* __restrict__ partial)
{
    __shared__ __align__(16) _Float16 Pt[PROWS * PSTRIDE];  // 38.2 KB
    __shared__ __align__(16) _Float16 hsA[2][2][2048];      // 16 KB
    const int t    = threadIdx.x;
    const int L    = t & 63;
    const int ut   = t >> 6;          // wave index = unit-tile 0..7
    const int b    = blockIdx.x >> 4;
    const int tile = blockIdx.x & 15;
    const int w0   = tile * WT;
    const int q  = L >> 4;
    const int ln = L & 15;
    const int j8 = L & 7;
    const int u  = ut * 16 + ln;      // this lane's hidden unit (B n-index)

    // ---- phase 1: x-proj (3 m-tiles = rows 0..47, stores clamped to 37) ----
    {
        f32x4 accx[3][4];   // [mt][gate], init with bias
#pragma unroll
        for (int g = 0; g < 4; ++g) {
            const float bg = b_ih[g * 128 + u] + b_hh[g * 128 + u];
            accx[0][g] = (f32x4){bg, bg, bg, bg};
            accx[1][g] = accx[0][g];
            accx[2][g] = accx[0][g];
        }
        int tok[3];
#pragma unroll
        for (int mt = 0; mt < 3; ++mt) {
            int s = w0 + mt * 16 + ln; s = s < 511 ? s : 511;  // clamp (masked at max)
            tok[mt] = inputs[b * Sn + s];
        }
#pragma unroll
        for (int ks = 0; ks < 4; ++ks) {
            half8 ax[3];
#pragma unroll
            for (int mt = 0; mt < 3; ++mt) {
                const float* er = embed + (size_t)tok[mt] * 128 + ks * 32 + q * 8;
                float4 e0 = *(const float4*)er;
                float4 e1 = *(const float4*)(er + 4);
                half8 a;
                a[0] = (_Float16)e0.x; a[1] = (_Float16)e0.y;
                a[2] = (_Float16)e0.z; a[3] = (_Float16)e0.w;
                a[4] = (_Float16)e1.x; a[5] = (_Float16)e1.y;
                a[6] = (_Float16)e1.z; a[7] = (_Float16)e1.w;
                ax[mt] = a;
            }
#pragma unroll
            for (int g = 0; g < 4; ++g) {
                half8 bw = *(const half8*)(wih_p + ((size_t)((g * 8 + ut) * 4 + ks) * 64 + L) * 8);
#pragma unroll
                for (int mt = 0; mt < 3; ++mt)
                    accx[mt][g] = __builtin_amdgcn_mfma_f32_16x16x32_f16(ax[mt], bw, accx[mt][g], 0, 0, 0);
            }
        }
        // store gate-interleaved fp16 Pt rows (predicated to 37 rows)
#pragma unroll
        for (int mt = 0; mt < 3; ++mt)
#pragma unroll
            for (int r = 0; r < 4; ++r) {
                const int sl = mt * 16 + q * 4 + r;
                if (sl < PROWS) {
                    half4 o;
                    o[0] = (_Float16)accx[mt][0][r];
                    o[1] = (_Float16)accx[mt][1][r];
                    o[2] = (_Float16)accx[mt][2][r];
                    o[3] = (_Float16)accx[mt][3][r];
                    *(half4*)&Pt[sl * PSTRIDE + u * 4] = o;
                }
            }
    }

    // register-resident w_hh B-fragments for this wave's unit-tile
    half8 whf[4][4];    // [gate][ks]
#pragma unroll
    for (int g = 0; g < 4; ++g)
#pragma unroll
        for (int ks = 0; ks < 4; ++ks)
            whf[g][ks] = *(const half8*)(whh_p + ((size_t)((g * 8 + ut) * 4 + ks) * 64 + L) * 8);

    __syncthreads();    // Pt visible to all waves

    // h scatter address components (A-fragment layout for unit u, window m)
    const int ks_h = ut >> 1;
    const int qp   = (ut & 1) * 2 + (ln >> 3);

    float cst[2][4] = {{0.f, 0.f, 0.f, 0.f}, {0.f, 0.f, 0.f, 0.f}};
    float hh[2][4];

    // ---- steps 0..5, two independent sub-tiles per barrier interval ----
    for (int st = 0; st < FWn; ++st) {
        if (st > 0) __syncthreads();        // prev step's h scatter visible
#pragma unroll
        for (int sub = 0; sub < 2; ++sub) {
            f32x4 acc[4];                   // [gate] over r
#pragma unroll
            for (int r = 0; r < 4; ++r) {
                half4 pv = *(const half4*)&Pt[(sub * 16 + q * 4 + r + st) * PSTRIDE + u * 4];
                acc[0][r] = (float)pv[0]; acc[1][r] = (float)pv[1];
                acc[2][r] = (float)pv[2]; acc[3][r] = (float)pv[3];
            }
            if (st > 0) {
                const _Float16* hb = hsA[(st + 1) & 1][sub];   // h(st-1)
#pragma unroll
                for (int ks = 0; ks < 4; ++ks) {
                    half8 ah = *(const half8*)(hb + (ks * 64 + L) * 8);
#pragma unroll
                    for (int g = 0; g < 4; ++g)
                        acc[g] = __builtin_amdgcn_mfma_f32_16x16x32_f16(ah, whf[g][ks], acc[g], 0, 0, 0);
                }
            }
            _Float16* buf = hsA[st & 1][sub];
#pragma unroll
            for (int r = 0; r < 4; ++r) {
                float ii = sigf(acc[0][r]);
                float ff = sigf(acc[1][r]);
                float gg = tanh_(acc[2][r]);
                float oo = sigf(acc[3][r]);
                float cc = ff * cst[sub][r] + ii * gg;
                cst[sub][r] = cc;
                hh[sub][r] = oo * tanh_(cc);
                if (st < FWn - 1)
                    buf[ks_h * 512 + (qp * 16 + q * 4 + r) * 8 + j8] = (_Float16)hh[sub][r];
            }
        }
    }

    // ---- max over this block's 32 windows (mask invalid), reduce across q ----
    float mv = -FLT_MAX;
#pragma unroll
    for (int sub = 0; sub < 2; ++sub)
#pragma unroll
        for (int r = 0; r < 4; ++r) {
            const int w = w0 + sub * 16 + q * 4 + r;
            if (w < Wn) mv = fmaxf(mv, hh[sub][r]);
        }
    mv = fmaxf(mv, __shfl_xor(mv, 16));
    mv = fmaxf(mv, __shfl_xor(mv, 32));
    if (q == 0)
        partial[(size_t)(b * NTILE + tile) * 128 + u] = mv;
}

// ---------------------------------------------------------------------------
// Kernel 2: feat[b][u] = max over tiles; out[b][c] = feat . fc_w[c] + fc_b[c]
// grid 64, block 128
// ---------------------------------------------------------------------------
__global__ void __launch_bounds__(128)
final_kernel(const float* __restrict__ partial, const float* __restrict__ fc_w,
             const float* __restrict__ fc_b, float* __restrict__ out)
{
    const int b = blockIdx.x;
    const int u = threadIdx.x;
    float m = -FLT_MAX;
#pragma unroll
    for (int tl = 0; tl < NTILE; ++tl)
        m = fmaxf(m, partial[(size_t)(b * NTILE + tl) * 128 + u]);
    float v0 = m * fc_w[u];
    float v1 = m * fc_w[128 + u];
#pragma unroll
    for (int off = 1; off < 64; off <<= 1) {
        v0 += __shfl_xor(v0, off);
        v1 += __shfl_xor(v1, off);
    }
    __shared__ float red[2][2];
    if ((u & 63) == 0) { red[u >> 6][0] = v0; red[u >> 6][1] = v1; }
    __syncthreads();
    if (u == 0) {
        out[b * 2 + 0] = red[0][0] + red[1][0] + fc_b[0];
        out[b * 2 + 1] = red[0][1] + red[1][1] + fc_b[1];
    }
}

// ---------------------------------------------------------------------------
extern "C" void kernel_launch(void* const* d_in, const int* in_sizes, int n_in,
                              void* d_out, int out_size, void* d_ws, size_t ws_size,
                              hipStream_t stream)
{
    const int*   inputs = (const int*)d_in[0];
    // d_in[1] = lengths : unused by the reference
    const float* embed  = (const float*)d_in[2];
    const float* w_ih   = (const float*)d_in[3];
    const float* w_hh   = (const float*)d_in[4];
    const float* b_ih   = (const float*)d_in[5];
    const float* b_hh   = (const float*)d_in[6];
    const float* fc_w   = (const float*)d_in[7];
    const float* fc_b   = (const float*)d_in[8];
    float* out = (float*)d_out;

    // workspace: partial (512 KiB) | wih_p, whh_p (128 KiB each)
    float*    partial = (float*)d_ws;
    _Float16* wih_p   = (_Float16*)(partial + Bn * NTILE * 128);
    _Float16* whh_p   = wih_p + 65536;

    pack_w_kernel<<<dim3(256), 256, 0, stream>>>(w_ih, w_hh, wih_p, whh_p);
    lstm_kernel<<<dim3(Bn * NTILE), 512, 0, stream>>>(inputs, embed, wih_p, whh_p,
                                                      b_ih, b_hh, partial);
    final_kernel<<<dim3(Bn), 128, 0, stream>>>(partial, fc_w, fc_b, out);
}